// Round 1
// baseline (1051.131 us; speedup 1.0000x reference)
//
#include <hip/hip_runtime.h>

#define N_ROWS 262144
#define HID 512
#define HHALF 256
#define HEADS 8
#define GNUM 1024
#define LN_EPS 1e-5f

typedef __bf16 bf16x8 __attribute__((ext_vector_type(8)));
typedef float f32x4 __attribute__((ext_vector_type(4)));

// ---------------- kernel 0: W1^T -> bf16, zero entropy slot ----------------
__global__ void k_prep(const float* __restrict__ W1, __bf16* __restrict__ w1t,
                       float* __restrict__ ent) {
    int tid = blockIdx.x * 256 + threadIdx.x;
    if (tid == 0) *ent = 0.f;
    if (tid < HID * HHALF) {
        int n = tid >> 9;   // 0..255 (output feature)
        int k = tid & 511;  // 0..511 (input feature)
        w1t[n * HID + k] = (__bf16)W1[k * HHALF + n];
    }
}

// ---------------- kernel 0b: segment starts (batch is sorted) ----------------
__global__ void k_seg(const int* __restrict__ batch, int* __restrict__ seg) {
    int g = blockIdx.x * 256 + threadIdx.x;
    if (g > GNUM) return;
    int lo = 0, hi = N_ROWS;
    while (lo < hi) {
        int mid = (lo + hi) >> 1;
        if (batch[mid] < g) lo = mid + 1; else hi = mid;
    }
    seg[g] = lo;
}

// ---------------- kernel 1: LayerNorm stats per row (1 wave = 1 row) ----------------
__global__ __launch_bounds__(256) void k_stats(const float* __restrict__ x,
                                               float2* __restrict__ stats) {
    int wid = threadIdx.x >> 6, lane = threadIdx.x & 63;
    int row = blockIdx.x * 4 + wid;
    const float* xr = x + (size_t)row * HID + lane * 8;
    float4 a = *(const float4*)xr;
    float4 b = *(const float4*)(xr + 4);
    float s = a.x + a.y + a.z + a.w + b.x + b.y + b.z + b.w;
    float q = a.x*a.x + a.y*a.y + a.z*a.z + a.w*a.w
            + b.x*b.x + b.y*b.y + b.z*b.z + b.w*b.w;
    #pragma unroll
    for (int m = 1; m < 64; m <<= 1) {
        s += __shfl_xor(s, m);
        q += __shfl_xor(q, m);
    }
    if (lane == 0) {
        float mu = s * (1.f / HID);
        float var = q * (1.f / HID) - mu * mu;
        stats[row] = make_float2(mu, rsqrtf(var + LN_EPS));
    }
}

// A-fragment build: load 8 f32, apply LN (x*rstd - mu*rstd)*gamma + beta, cast bf16
__device__ inline bf16x8 make_af(const float* xp, const float* gp, const float* bp,
                                 float rstd, float nmr) {
    float4 xa = *(const float4*)xp;
    float4 xb = *(const float4*)(xp + 4);
    float4 ga = *(const float4*)gp;
    float4 gb = *(const float4*)(gp + 4);
    float4 ba = *(const float4*)bp;
    float4 bb = *(const float4*)(bp + 4);
    float xs[8] = {xa.x, xa.y, xa.z, xa.w, xb.x, xb.y, xb.z, xb.w};
    float gs[8] = {ga.x, ga.y, ga.z, ga.w, gb.x, gb.y, gb.z, gb.w};
    float bs[8] = {ba.x, ba.y, ba.z, ba.w, bb.x, bb.y, bb.z, bb.w};
    bf16x8 r;
    #pragma unroll
    for (int j = 0; j < 8; ++j)
        r[j] = (__bf16)fmaf(fmaf(xs[j], rstd, nmr), gs[j], bs[j]);
    return r;
}

// ---------------- kernel 2: fused LN-apply + GEMM(512->256) + silu + W2 -> logits ----------------
// block = 256 thr (4 waves); block tile = 64 rows; wave tile = 16 rows x 256 cols.
// B (W1^T bf16) staged per 64-wide K-chunk in LDS, row stride 72 bf16 (144B) to kill conflicts.
__global__ __launch_bounds__(256) void k_gemm(
    const float* __restrict__ x, const float2* __restrict__ stats,
    const float* __restrict__ gamma, const float* __restrict__ beta,
    const __bf16* __restrict__ w1t, const float* __restrict__ b1,
    const float* __restrict__ W2, const float* __restrict__ b2,
    float* __restrict__ logits)
{
    __shared__ __align__(16) __bf16 ldsb[256 * 72];
    const int tid = threadIdx.x;
    const int wid = tid >> 6, lane = tid & 63;
    const int q = lane >> 4, c = lane & 15;
    const int rowbase = blockIdx.x * 64 + wid * 16;

    f32x4 acc[16];
    #pragma unroll
    for (int t = 0; t < 16; ++t) acc[t] = (f32x4)0.f;

    const int arow = rowbase + c;           // A-operand row for this lane
    float2 st = stats[arow];
    const float rstd = st.y;
    const float nmr = -st.x * st.y;         // -mu*rstd
    const float* xrow = x + (size_t)arow * HID;

    const int nrow = tid >> 3, seg = tid & 7;  // staging map: 8 thr per 128B row-chunk

    for (int s8 = 0; s8 < 8; ++s8) {
        const int k0 = s8 * 64;
        __syncthreads();
        #pragma unroll
        for (int it = 0; it < 8; ++it) {
            int n = nrow + it * 32;
            *(uint4*)(ldsb + n * 72 + seg * 8) =
                *(const uint4*)(w1t + n * HID + k0 + seg * 8);
        }
        __syncthreads();

        bf16x8 af0 = make_af(xrow + k0 + q * 8, gamma + k0 + q * 8, beta + k0 + q * 8,
                             rstd, nmr);
        bf16x8 af1 = make_af(xrow + k0 + 32 + q * 8, gamma + k0 + 32 + q * 8,
                             beta + k0 + 32 + q * 8, rstd, nmr);
        #pragma unroll
        for (int t = 0; t < 16; ++t) {
            int n = t * 16 + c;
            bf16x8 bf0 = *(const bf16x8*)(ldsb + n * 72 + q * 8);
            bf16x8 bf1 = *(const bf16x8*)(ldsb + n * 72 + 32 + q * 8);
            acc[t] = __builtin_amdgcn_mfma_f32_16x16x32_bf16(af0, bf0, acc[t], 0, 0, 0);
            acc[t] = __builtin_amdgcn_mfma_f32_16x16x32_bf16(af1, bf1, acc[t], 0, 0, 0);
        }
    }

    // epilogue: h = silu(acc + b1); logits partial = h @ W2; reduce over the 16 lanes (c)
    float lp[4][8];
    #pragma unroll
    for (int r = 0; r < 4; ++r)
        #pragma unroll
        for (int hd = 0; hd < 8; ++hd) lp[r][hd] = 0.f;

    #pragma unroll
    for (int t = 0; t < 16; ++t) {
        int n = t * 16 + c;
        float b1v = b1[n];
        float4 w2a = *(const float4*)(W2 + n * 8);
        float4 w2b = *(const float4*)(W2 + n * 8 + 4);
        #pragma unroll
        for (int r = 0; r < 4; ++r) {
            float v = acc[t][r] + b1v;
            float h = v / (1.f + __expf(-v));   // silu
            lp[r][0] = fmaf(h, w2a.x, lp[r][0]);
            lp[r][1] = fmaf(h, w2a.y, lp[r][1]);
            lp[r][2] = fmaf(h, w2a.z, lp[r][2]);
            lp[r][3] = fmaf(h, w2a.w, lp[r][3]);
            lp[r][4] = fmaf(h, w2b.x, lp[r][4]);
            lp[r][5] = fmaf(h, w2b.y, lp[r][5]);
            lp[r][6] = fmaf(h, w2b.z, lp[r][6]);
            lp[r][7] = fmaf(h, w2b.w, lp[r][7]);
        }
    }
    #pragma unroll
    for (int m = 1; m < 16; m <<= 1)
        #pragma unroll
        for (int r = 0; r < 4; ++r)
            #pragma unroll
            for (int hd = 0; hd < 8; ++hd)
                lp[r][hd] += __shfl_xor(lp[r][hd], m);

    if (c == 0) {
        float4 b2a = *(const float4*)b2;
        float4 b2b = *(const float4*)(b2 + 4);
        #pragma unroll
        for (int r = 0; r < 4; ++r) {
            int orow = rowbase + q * 4 + r;   // D layout: row = quad*4 + reg
            float4 o0 = {lp[r][0] + b2a.x, lp[r][1] + b2a.y,
                         lp[r][2] + b2a.z, lp[r][3] + b2a.w};
            float4 o1 = {lp[r][4] + b2b.x, lp[r][5] + b2b.y,
                         lp[r][6] + b2b.z, lp[r][7] + b2b.w};
            *(float4*)(logits + (size_t)orow * 8) = o0;
            *(float4*)(logits + (size_t)orow * 8 + 4) = o1;
        }
    }
}

// ---------------- kernel 3: per-graph segment softmax + weighted pool + entropy ----------------
__global__ __launch_bounds__(256) void k_pool(
    const float* __restrict__ x, const float* __restrict__ logits,
    const int* __restrict__ seg, float* __restrict__ graph_z,
    float* __restrict__ weights, float* __restrict__ ent)
{
    const int g = blockIdx.x;
    const int tid = threadIdx.x;
    const int s = seg[g], e = seg[g + 1];
    const int nrows = e - s;
    __shared__ float smax[8], sinv[8];
    __shared__ float red[4][8];
    __shared__ __align__(16) float wbuf[32][8];

    float acc0 = 0.f, acc1 = 0.f;
    float entl = 0.f;

    if (nrows > 0) {
        const int wid = tid >> 6, lane = tid & 63;
        // ---- phase A: per-head max
        float mx[8];
        #pragma unroll
        for (int h = 0; h < 8; ++h) mx[h] = -1e30f;
        for (int i = s + tid; i < e; i += 256) {
            float4 l0 = *(const float4*)(logits + (size_t)i * 8);
            float4 l1 = *(const float4*)(logits + (size_t)i * 8 + 4);
            mx[0] = fmaxf(mx[0], l0.x); mx[1] = fmaxf(mx[1], l0.y);
            mx[2] = fmaxf(mx[2], l0.z); mx[3] = fmaxf(mx[3], l0.w);
            mx[4] = fmaxf(mx[4], l1.x); mx[5] = fmaxf(mx[5], l1.y);
            mx[6] = fmaxf(mx[6], l1.z); mx[7] = fmaxf(mx[7], l1.w);
        }
        #pragma unroll
        for (int m = 1; m < 64; m <<= 1)
            #pragma unroll
            for (int h = 0; h < 8; ++h) mx[h] = fmaxf(mx[h], __shfl_xor(mx[h], m));
        if (lane == 0) {
            #pragma unroll
            for (int h = 0; h < 8; ++h) red[wid][h] = mx[h];
        }
        __syncthreads();
        if (tid < 8)
            smax[tid] = fmaxf(fmaxf(red[0][tid], red[1][tid]),
                              fmaxf(red[2][tid], red[3][tid]));
        __syncthreads();
        // ---- phase B: sum of exp
        float sm[8];
        #pragma unroll
        for (int h = 0; h < 8; ++h) sm[h] = smax[h];
        float su[8] = {0, 0, 0, 0, 0, 0, 0, 0};
        for (int i = s + tid; i < e; i += 256) {
            float4 l0 = *(const float4*)(logits + (size_t)i * 8);
            float4 l1 = *(const float4*)(logits + (size_t)i * 8 + 4);
            su[0] += __expf(l0.x - sm[0]); su[1] += __expf(l0.y - sm[1]);
            su[2] += __expf(l0.z - sm[2]); su[3] += __expf(l0.w - sm[3]);
            su[4] += __expf(l1.x - sm[4]); su[5] += __expf(l1.y - sm[5]);
            su[6] += __expf(l1.z - sm[6]); su[7] += __expf(l1.w - sm[7]);
        }
        #pragma unroll
        for (int m = 1; m < 64; m <<= 1)
            #pragma unroll
            for (int h = 0; h < 8; ++h) su[h] += __shfl_xor(su[h], m);
        if (lane == 0) {
            #pragma unroll
            for (int h = 0; h < 8; ++h) red[wid][h] = su[h];
        }
        __syncthreads();
        if (tid < 8) {
            float d = red[0][tid] + red[1][tid] + red[2][tid] + red[3][tid];
            sinv[tid] = 1.f / (d > 0.f ? d : 1.f);
        }
        __syncthreads();
        // ---- phase C: weights + entropy + weighted feature pooling
        const int r = tid >> 3, h = tid & 7;
        const float smh = smax[h], ivh = sinv[h];
        const int h0 = tid >> 6, h1 = 4 + (tid >> 6);
        for (int base = 0; base < nrows; base += 32) {
            if (base + r < nrows) {
                int i = s + base + r;
                float w = __expf(logits[(size_t)i * 8 + h] - smh) * ivh;
                wbuf[r][h] = w;
                weights[(size_t)i * 8 + h] = w;
                entl += w * __logf(w + 1e-8f);
            }
            __syncthreads();
            int lim = min(32, nrows - base);
            for (int r2 = 0; r2 < lim; ++r2) {
                const float* xp = x + (size_t)(s + base + r2) * HID;
                acc0 = fmaf(xp[tid], wbuf[r2][h0], acc0);
                acc1 = fmaf(xp[tid + 256], wbuf[r2][h1], acc1);
            }
            __syncthreads();
        }
    }
    graph_z[(size_t)g * HID + tid] = acc0;
    graph_z[(size_t)g * HID + tid + 256] = acc1;

    // ---- entropy reduction: mean_entropy = -(1/(G*8)) * sum w*log(w+eps)
    #pragma unroll
    for (int m = 1; m < 64; m <<= 1) entl += __shfl_xor(entl, m);
    __syncthreads();
    if ((tid & 63) == 0) red[0][tid >> 6] = entl;
    __syncthreads();
    if (tid == 0) {
        float tot = red[0][0] + red[0][1] + red[0][2] + red[0][3];
        atomicAdd(ent, tot * (-1.f / (GNUM * 8.f)));
    }
}

extern "C" void kernel_launch(void* const* d_in, const int* in_sizes, int n_in,
                              void* d_out, int out_size, void* d_ws, size_t ws_size,
                              hipStream_t stream)
{
    const float* x     = (const float*)d_in[0];
    const int*   batch = (const int*)d_in[1];
    const float* gamma = (const float*)d_in[2];
    const float* beta  = (const float*)d_in[3];
    const float* W1    = (const float*)d_in[4];
    const float* b1    = (const float*)d_in[5];
    const float* W2    = (const float*)d_in[6];
    const float* b2    = (const float*)d_in[7];

    char* ws = (char*)d_ws;
    float2* stats  = (float2*)ws;                                   // 2 MB
    float*  logits = (float*)(ws + (size_t)2 * 1024 * 1024);        // 8 MB
    __bf16* w1t    = (__bf16*)(ws + (size_t)10 * 1024 * 1024);      // 256 KB
    int*    seg    = (int*)(ws + (size_t)10 * 1024 * 1024 + 512 * 1024);  // 4.1 KB

    float* out     = (float*)d_out;
    float* graph_z = out;                                           // [G,512]
    float* weights = out + (size_t)GNUM * HID;                      // [N,8]
    float* ent     = out + (size_t)GNUM * HID + (size_t)N_ROWS * HEADS; // scalar

    k_prep <<<512, 256, 0, stream>>>(W1, w1t, ent);
    k_seg  <<<5, 256, 0, stream>>>(batch, seg);
    k_stats<<<N_ROWS / 4, 256, 0, stream>>>(x, stats);
    k_gemm <<<N_ROWS / 64, 256, 0, stream>>>(x, stats, gamma, beta, w1t, b1, W2, b2, logits);
    k_pool <<<GNUM, 256, 0, stream>>>(x, logits, seg, graph_z, weights, ent);
}